// Round 12
// baseline (169.303 us; speedup 1.0000x reference)
//
#include <hip/hip_runtime.h>

// RNN: h_{t+1} = relu(x_t*W_ih^T + b_ih + b_hh + W_hh·h_t), out = fc(h_T).
// B=4096, T=1000, H=20.  16 lanes per batch, 1024 waves = 1 per SIMD.
//
// Alternating-role scheme (R6+): lane (a,bq) of each 16-lane group:
//   EVEN step: rows a-group x k-slice bq; reduce over bq = quad_perm butterfly.
//   ODD  step: rows bq-group x k-slice a; reduce over a = row_ror:4/8 folds.
// R9: 20-step block prefetch fixed the x-latency stall (140 -> 102 us).
// R10/R11: asm folds with "+v"(a) : "v"(a) added ~10 operand-copy movs/step
// (busy 76 -> 83-87 us) -> regression. This round: SINGLE-operand asm fold
//   v_add_f32_dpp %0, %0, %0  (dst = dpp(src0) + src1, all the same reg)
// -> guaranteed ONE instruction, no copy movs possible. If R9's intrinsic
// folds were lowering to mov0+mov_dpp+add (3x), this cuts ~20 insts/step.

#define TT 1000

struct F5 { float v0, v1, v2, v3, v4; };

#define PIN(v) asm volatile("" : "+v"(v))
__device__ __forceinline__ void pin5(F5& f) {
    PIN(f.v0); PIN(f.v1); PIN(f.v2); PIN(f.v3); PIN(f.v4);
}
__device__ __forceinline__ void keep5(const F5& f) {
    asm volatile("" :: "v"(f.v0), "v"(f.v1), "v"(f.v2), "v"(f.v3), "v"(f.v4));
}

// fused fold: a = dpp(a) + a -- ONE instruction, ONE operand (no copy movs).
#define FOLD_QP1(a)  asm("v_add_f32_dpp %0, %0, %0 quad_perm:[1,0,3,2] row_mask:0xf bank_mask:0xf" : "+v"(a))
#define FOLD_QP2(a)  asm("v_add_f32_dpp %0, %0, %0 quad_perm:[2,3,0,1] row_mask:0xf bank_mask:0xf" : "+v"(a))
#define FOLD_ROR4(a) asm("v_add_f32_dpp %0, %0, %0 row_ror:4 row_mask:0xf bank_mask:0xf" : "+v"(a))
#define FOLD_ROR8(a) asm("v_add_f32_dpp %0, %0, %0 row_ror:8 row_mask:0xf bank_mask:0xf" : "+v"(a))

// One timestep, breadth-first, column-major tile (wck.vj = W[row j][col k]).
template <bool EVEN>
__device__ __forceinline__ void step(float xt, F5& h,
                                     const F5& wc0, const F5& wc1,
                                     const F5& wc2, const F5& wc3,
                                     const F5& wc4,
                                     const F5& wih, const F5& bias) {
    float a0 = __builtin_fmaf(xt, wih.v0, bias.v0);
    float a1 = __builtin_fmaf(xt, wih.v1, bias.v1);
    float a2 = __builtin_fmaf(xt, wih.v2, bias.v2);
    float a3 = __builtin_fmaf(xt, wih.v3, bias.v3);
    float a4 = __builtin_fmaf(xt, wih.v4, bias.v4);

#define KCOL(hk, wc)                              \
    a0 = __builtin_fmaf(hk, (wc).v0, a0);         \
    a1 = __builtin_fmaf(hk, (wc).v1, a1);         \
    a2 = __builtin_fmaf(hk, (wc).v2, a2);         \
    a3 = __builtin_fmaf(hk, (wc).v3, a3);         \
    a4 = __builtin_fmaf(hk, (wc).v4, a4);
    KCOL(h.v0, wc0) KCOL(h.v1, wc1) KCOL(h.v2, wc2) KCOL(h.v3, wc3) KCOL(h.v4, wc4)
#undef KCOL

    if constexpr (EVEN) {
        FOLD_QP1(a0); FOLD_QP1(a1); FOLD_QP1(a2); FOLD_QP1(a3); FOLD_QP1(a4);
        FOLD_QP2(a0); FOLD_QP2(a1); FOLD_QP2(a2); FOLD_QP2(a3); FOLD_QP2(a4);
    } else {
        FOLD_ROR4(a0); FOLD_ROR4(a1); FOLD_ROR4(a2); FOLD_ROR4(a3); FOLD_ROR4(a4);
        FOLD_ROR8(a0); FOLD_ROR8(a1); FOLD_ROR8(a2); FOLD_ROR8(a3); FOLD_ROR8(a4);
    }

    h.v0 = fmaxf(a0, 0.f); h.v1 = fmaxf(a1, 0.f); h.v2 = fmaxf(a2, 0.f);
    h.v3 = fmaxf(a3, 0.f); h.v4 = fmaxf(a4, 0.f);
}

__global__ void
__attribute__((amdgpu_flat_work_group_size(64, 64), amdgpu_waves_per_eu(1, 1)))
rnn_sop_kernel(const float* __restrict__ x,
               const float* __restrict__ W_ih,
               const float* __restrict__ W_hh,
               const float* __restrict__ b_ih,
               const float* __restrict__ b_hh,
               const float* __restrict__ fc_w,
               const float* __restrict__ fc_b,
               float* __restrict__ out) {
    const int tid = blockIdx.x * 64 + threadIdx.x;
    const int b   = tid >> 4;     // batch element
    const int gl  = tid & 15;     // lane in 16-lane group
    const int a   = gl >> 2;      // quad index
    const int bq  = gl & 3;       // position in quad

    // --- weight tiles, column-major
    F5 we0, we1, we2, we3, we4;   // wek.vj = W[a*5+j][bq*5+k]
    F5 wo0, wo1, wo2, wo3, wo4;   // wok.vj = W[bq*5+j][a*5+k]
#define LOADC(wk, k, rbase, cbase)                                           \
    { (wk).v0 = W_hh[((rbase) + 0) * 20 + (cbase) + (k)];                    \
      (wk).v1 = W_hh[((rbase) + 1) * 20 + (cbase) + (k)];                    \
      (wk).v2 = W_hh[((rbase) + 2) * 20 + (cbase) + (k)];                    \
      (wk).v3 = W_hh[((rbase) + 3) * 20 + (cbase) + (k)];                    \
      (wk).v4 = W_hh[((rbase) + 4) * 20 + (cbase) + (k)]; }
    LOADC(we0, 0, a * 5, bq * 5) LOADC(we1, 1, a * 5, bq * 5)
    LOADC(we2, 2, a * 5, bq * 5) LOADC(we3, 3, a * 5, bq * 5)
    LOADC(we4, 4, a * 5, bq * 5)
    LOADC(wo0, 0, bq * 5, a * 5) LOADC(wo1, 1, bq * 5, a * 5)
    LOADC(wo2, 2, bq * 5, a * 5) LOADC(wo3, 3, bq * 5, a * 5)
    LOADC(wo4, 4, bq * 5, a * 5)
#undef LOADC

    const bool eact = (bq == 0);
    const bool oact = (a == 0);
    F5 wie, bie, wio, bio;
    {
        const float* pw = W_ih + a * 5;
        const float* p1 = b_ih + a * 5;
        const float* p2 = b_hh + a * 5;
        wie.v0 = eact ? pw[0] : 0.f;  bie.v0 = eact ? (p1[0] + p2[0]) : 0.f;
        wie.v1 = eact ? pw[1] : 0.f;  bie.v1 = eact ? (p1[1] + p2[1]) : 0.f;
        wie.v2 = eact ? pw[2] : 0.f;  bie.v2 = eact ? (p1[2] + p2[2]) : 0.f;
        wie.v3 = eact ? pw[3] : 0.f;  bie.v3 = eact ? (p1[3] + p2[3]) : 0.f;
        wie.v4 = eact ? pw[4] : 0.f;  bie.v4 = eact ? (p1[4] + p2[4]) : 0.f;
    }
    {
        const float* pw = W_ih + bq * 5;
        const float* p1 = b_ih + bq * 5;
        const float* p2 = b_hh + bq * 5;
        wio.v0 = oact ? pw[0] : 0.f;  bio.v0 = oact ? (p1[0] + p2[0]) : 0.f;
        wio.v1 = oact ? pw[1] : 0.f;  bio.v1 = oact ? (p1[1] + p2[1]) : 0.f;
        wio.v2 = oact ? pw[2] : 0.f;  bio.v2 = oact ? (p1[2] + p2[2]) : 0.f;
        wio.v3 = oact ? pw[3] : 0.f;  bio.v3 = oact ? (p1[3] + p2[3]) : 0.f;
        wio.v4 = oact ? pw[4] : 0.f;  bio.v4 = oact ? (p1[4] + p2[4]) : 0.f;
    }

    pin5(we0); pin5(we1); pin5(we2); pin5(we3); pin5(we4);
    pin5(wo0); pin5(wo1); pin5(wo2); pin5(wo3); pin5(wo4);
    pin5(wie); pin5(bie); pin5(wio); pin5(bio);

    F5 h = {0.f, 0.f, 0.f, 0.f, 0.f};

    const float* __restrict__ xb = x + (size_t)b * TT;

    // --- 20-step register blocks, double-buffered (R9 structure)
#define LOAD5(P0, P1, P2, P3, P4, off)                  \
    P0 = *(const float4*)(xb + (off));                  \
    P1 = *(const float4*)(xb + (off) + 4);              \
    P2 = *(const float4*)(xb + (off) + 8);              \
    P3 = *(const float4*)(xb + (off) + 12);             \
    P4 = *(const float4*)(xb + (off) + 16);

#define STEP_E(xv) step<true >(xv, h, we0, we1, we2, we3, we4, wie, bie);
#define STEP_O(xv) step<false>(xv, h, wo0, wo1, wo2, wo3, wo4, wio, bio);
#define RUN4(Q)  STEP_E(Q.x) STEP_O(Q.y) STEP_E(Q.z) STEP_O(Q.w)
#define RUN20(P0, P1, P2, P3, P4) RUN4(P0) RUN4(P1) RUN4(P2) RUN4(P3) RUN4(P4)

    float4 A0, A1, A2, A3, A4, B0, B1, B2, B3, B4;
    LOAD5(A0, A1, A2, A3, A4, 0)    // block 0: steps 0..19
    LOAD5(B0, B1, B2, B3, B4, 20)   // block 1: steps 20..39

    for (int it = 0; it < 25; ++it) {
        const int base = it * 40;
        const int na = (it < 24) ? base + 40 : 920;  // clamped; stale data unused
        const int nb = (it < 24) ? base + 60 : 940;

        RUN20(A0, A1, A2, A3, A4)
        LOAD5(A0, A1, A2, A3, A4, na)
        RUN20(B0, B1, B2, B3, B4)
        LOAD5(B0, B1, B2, B3, B4, nb)
    }

#undef RUN20
#undef RUN4
#undef STEP_E
#undef STEP_O
#undef LOAD5

    keep5(we0); keep5(we1); keep5(we2); keep5(we3); keep5(we4);
    keep5(wo0); keep5(wo1); keep5(wo2); keep5(wo3); keep5(wo4);
    keep5(wie); keep5(bie); keep5(wio); keep5(bio);

    // After step 999 (odd role), lane (a,bq) holds h[bq-slice] replicated
    // over a. Mask fc weights to a==0 lanes, dot, reduce across the group.
    float dot;
    {
        const float* pf = fc_w + bq * 5;
        float f0 = oact ? pf[0] : 0.f, f1 = oact ? pf[1] : 0.f;
        float f2 = oact ? pf[2] : 0.f, f3 = oact ? pf[3] : 0.f;
        float f4 = oact ? pf[4] : 0.f;
        dot = h.v0 * f0;
        dot = __builtin_fmaf(h.v1, f1, dot);
        dot = __builtin_fmaf(h.v2, f2, dot);
        dot = __builtin_fmaf(h.v3, f3, dot);
        dot = __builtin_fmaf(h.v4, f4, dot);
    }
    dot += __shfl_xor(dot, 1, 16);
    dot += __shfl_xor(dot, 2, 16);
    dot += __shfl_xor(dot, 4, 16);
    dot += __shfl_xor(dot, 8, 16);

    if (gl == 0)
        out[b] = dot + fc_b[0];
}

extern "C" void kernel_launch(void* const* d_in, const int* in_sizes, int n_in,
                              void* d_out, int out_size, void* d_ws, size_t ws_size,
                              hipStream_t stream) {
    const float* x    = (const float*)d_in[0];
    const float* W_ih = (const float*)d_in[1];
    const float* W_hh = (const float*)d_in[2];
    const float* b_ih = (const float*)d_in[3];
    const float* b_hh = (const float*)d_in[4];
    const float* fc_w = (const float*)d_in[5];
    const float* fc_b = (const float*)d_in[6];
    float* out = (float*)d_out;

    // 4096 batches * 16 lanes = 65536 threads; 64-thread blocks -> 1024
    // single-wave blocks, one per SIMD.
    const int block = 64;
    const int grid  = (4096 * 16) / block;  // 1024 blocks
    rnn_sop_kernel<<<grid, block, 0, stream>>>(x, W_ih, W_hh, b_ih, b_hh,
                                               fc_w, fc_b, out);
}

// Round 13
// 158.883 us; speedup vs baseline: 1.0656x; 1.0656x over previous
//
#include <hip/hip_runtime.h>

// RNN: h_{t+1} = relu(x_t*W_ih^T + b_ih + b_hh + W_hh·h_t), out = fc(h_T).
// B=4096, T=1000, H=20.  16 lanes per batch, 1024 waves = 1 per SIMD.
//
// Alternating-role scheme: lane (a,bq) of each 16-lane group:
//   EVEN step: rows a-group x k-slice bq; reduce over bq = quad_perm butterfly.
//   ODD  step: rows bq-group x k-slice a; reduce over a = row_ror:4/8 folds.
// Step = 30 FMA + 10 fold + 5 max (floor for this decomposition).
//
// History: R9 intrinsic folds + 20-step block prefetch = 102 us (best).
// R10-R12: all inline-asm fold variants = 112 us -- asm blocks the scheduler
// (loses cross-step weave), NOT operand copies. Reverted to intrinsics.
// R13: 40-step prefetch blocks (12 x 80-step iters + 40-step tail) -- halves
// the vmcnt boundaries (50 -> 25) and doubles load-to-use slack (~4400 cyc).

#define TT 1000

struct F5 { float v0, v1, v2, v3, v4; };

#define PIN(v) asm volatile("" : "+v"(v))
__device__ __forceinline__ void pin5(F5& f) {
    PIN(f.v0); PIN(f.v1); PIN(f.v2); PIN(f.v3); PIN(f.v4);
}
__device__ __forceinline__ void keep5(const F5& f) {
    asm volatile("" :: "v"(f.v0), "v"(f.v1), "v"(f.v2), "v"(f.v3), "v"(f.v4));
}

template <int CTRL>
__device__ __forceinline__ float dpp_f(float v) {
    // old=0 (= add identity) + bound_ctrl + full masks -> GCNDPPCombine can
    // fuse the mov_dpp into the consuming v_add -> v_add_f32_dpp.
    return __int_as_float(__builtin_amdgcn_update_dpp(
        0, __float_as_int(v), CTRL, 0xF, 0xF, true));
}

#define QP_XOR1 0xB1   // quad_perm [1,0,3,2]
#define QP_XOR2 0x4E   // quad_perm [2,3,0,1]
#define ROR4   0x124   // row_ror:4  (within 16-lane row)
#define ROR8   0x128   // row_ror:8

// One timestep, breadth-first, column-major tile (wck.vj = W[row j][col k]).
template <int C1, int C2>
__device__ __forceinline__ void step(float xt, F5& h,
                                     const F5& wc0, const F5& wc1,
                                     const F5& wc2, const F5& wc3,
                                     const F5& wc4,
                                     const F5& wih, const F5& bias) {
    float a0 = __builtin_fmaf(xt, wih.v0, bias.v0);
    float a1 = __builtin_fmaf(xt, wih.v1, bias.v1);
    float a2 = __builtin_fmaf(xt, wih.v2, bias.v2);
    float a3 = __builtin_fmaf(xt, wih.v3, bias.v3);
    float a4 = __builtin_fmaf(xt, wih.v4, bias.v4);

#define KCOL(hk, wc)                              \
    a0 = __builtin_fmaf(hk, (wc).v0, a0);         \
    a1 = __builtin_fmaf(hk, (wc).v1, a1);         \
    a2 = __builtin_fmaf(hk, (wc).v2, a2);         \
    a3 = __builtin_fmaf(hk, (wc).v3, a3);         \
    a4 = __builtin_fmaf(hk, (wc).v4, a4);
    KCOL(h.v0, wc0) KCOL(h.v1, wc1) KCOL(h.v2, wc2) KCOL(h.v3, wc3) KCOL(h.v4, wc4)
#undef KCOL

    {
        float t0 = dpp_f<C1>(a0), t1 = dpp_f<C1>(a1), t2 = dpp_f<C1>(a2),
              t3 = dpp_f<C1>(a3), t4 = dpp_f<C1>(a4);
        a0 += t0; a1 += t1; a2 += t2; a3 += t3; a4 += t4;
    }
    {
        float t0 = dpp_f<C2>(a0), t1 = dpp_f<C2>(a1), t2 = dpp_f<C2>(a2),
              t3 = dpp_f<C2>(a3), t4 = dpp_f<C2>(a4);
        a0 += t0; a1 += t1; a2 += t2; a3 += t3; a4 += t4;
    }

    h.v0 = fmaxf(a0, 0.f); h.v1 = fmaxf(a1, 0.f); h.v2 = fmaxf(a2, 0.f);
    h.v3 = fmaxf(a3, 0.f); h.v4 = fmaxf(a4, 0.f);
}

__global__ void
__attribute__((amdgpu_flat_work_group_size(64, 64), amdgpu_waves_per_eu(1, 1)))
rnn_d40_kernel(const float* __restrict__ x,
               const float* __restrict__ W_ih,
               const float* __restrict__ W_hh,
               const float* __restrict__ b_ih,
               const float* __restrict__ b_hh,
               const float* __restrict__ fc_w,
               const float* __restrict__ fc_b,
               float* __restrict__ out) {
    const int tid = blockIdx.x * 64 + threadIdx.x;
    const int b   = tid >> 4;     // batch element
    const int gl  = tid & 15;     // lane in 16-lane group
    const int a   = gl >> 2;      // quad index
    const int bq  = gl & 3;       // position in quad

    // --- weight tiles, column-major
    F5 we0, we1, we2, we3, we4;   // wek.vj = W[a*5+j][bq*5+k]
    F5 wo0, wo1, wo2, wo3, wo4;   // wok.vj = W[bq*5+j][a*5+k]
#define LOADC(wk, k, rbase, cbase)                                           \
    { (wk).v0 = W_hh[((rbase) + 0) * 20 + (cbase) + (k)];                    \
      (wk).v1 = W_hh[((rbase) + 1) * 20 + (cbase) + (k)];                    \
      (wk).v2 = W_hh[((rbase) + 2) * 20 + (cbase) + (k)];                    \
      (wk).v3 = W_hh[((rbase) + 3) * 20 + (cbase) + (k)];                    \
      (wk).v4 = W_hh[((rbase) + 4) * 20 + (cbase) + (k)]; }
    LOADC(we0, 0, a * 5, bq * 5) LOADC(we1, 1, a * 5, bq * 5)
    LOADC(we2, 2, a * 5, bq * 5) LOADC(we3, 3, a * 5, bq * 5)
    LOADC(we4, 4, a * 5, bq * 5)
    LOADC(wo0, 0, bq * 5, a * 5) LOADC(wo1, 1, bq * 5, a * 5)
    LOADC(wo2, 2, bq * 5, a * 5) LOADC(wo3, 3, bq * 5, a * 5)
    LOADC(wo4, 4, bq * 5, a * 5)
#undef LOADC

    const bool eact = (bq == 0);
    const bool oact = (a == 0);
    F5 wie, bie, wio, bio;
    {
        const float* pw = W_ih + a * 5;
        const float* p1 = b_ih + a * 5;
        const float* p2 = b_hh + a * 5;
        wie.v0 = eact ? pw[0] : 0.f;  bie.v0 = eact ? (p1[0] + p2[0]) : 0.f;
        wie.v1 = eact ? pw[1] : 0.f;  bie.v1 = eact ? (p1[1] + p2[1]) : 0.f;
        wie.v2 = eact ? pw[2] : 0.f;  bie.v2 = eact ? (p1[2] + p2[2]) : 0.f;
        wie.v3 = eact ? pw[3] : 0.f;  bie.v3 = eact ? (p1[3] + p2[3]) : 0.f;
        wie.v4 = eact ? pw[4] : 0.f;  bie.v4 = eact ? (p1[4] + p2[4]) : 0.f;
    }
    {
        const float* pw = W_ih + bq * 5;
        const float* p1 = b_ih + bq * 5;
        const float* p2 = b_hh + bq * 5;
        wio.v0 = oact ? pw[0] : 0.f;  bio.v0 = oact ? (p1[0] + p2[0]) : 0.f;
        wio.v1 = oact ? pw[1] : 0.f;  bio.v1 = oact ? (p1[1] + p2[1]) : 0.f;
        wio.v2 = oact ? pw[2] : 0.f;  bio.v2 = oact ? (p1[2] + p2[2]) : 0.f;
        wio.v3 = oact ? pw[3] : 0.f;  bio.v3 = oact ? (p1[3] + p2[3]) : 0.f;
        wio.v4 = oact ? pw[4] : 0.f;  bio.v4 = oact ? (p1[4] + p2[4]) : 0.f;
    }

    pin5(we0); pin5(we1); pin5(we2); pin5(we3); pin5(we4);
    pin5(wo0); pin5(wo1); pin5(wo2); pin5(wo3); pin5(wo4);
    pin5(wie); pin5(bie); pin5(wio); pin5(bio);

    F5 h = {0.f, 0.f, 0.f, 0.f, 0.f};

    const float* __restrict__ xb = x + (size_t)b * TT;

    // --- 40-step register blocks (10 float4 each), double-buffered.
#define LOAD10(P, off)                                  \
    P##0 = *(const float4*)(xb + (off));                \
    P##1 = *(const float4*)(xb + (off) + 4);            \
    P##2 = *(const float4*)(xb + (off) + 8);            \
    P##3 = *(const float4*)(xb + (off) + 12);           \
    P##4 = *(const float4*)(xb + (off) + 16);           \
    P##5 = *(const float4*)(xb + (off) + 20);           \
    P##6 = *(const float4*)(xb + (off) + 24);           \
    P##7 = *(const float4*)(xb + (off) + 28);           \
    P##8 = *(const float4*)(xb + (off) + 32);           \
    P##9 = *(const float4*)(xb + (off) + 36);

#define STEP_E(xv) step<QP_XOR1, QP_XOR2>(xv, h, we0, we1, we2, we3, we4, wie, bie);
#define STEP_O(xv) step<ROR4,    ROR8   >(xv, h, wo0, wo1, wo2, wo3, wo4, wio, bio);
#define RUN4(Q)  STEP_E(Q.x) STEP_O(Q.y) STEP_E(Q.z) STEP_O(Q.w)
#define RUN40(P) RUN4(P##0) RUN4(P##1) RUN4(P##2) RUN4(P##3) RUN4(P##4) \
                 RUN4(P##5) RUN4(P##6) RUN4(P##7) RUN4(P##8) RUN4(P##9)

    float4 A0, A1, A2, A3, A4, A5, A6, A7, A8, A9;
    float4 B0, B1, B2, B3, B4, B5, B6, B7, B8, B9;
    LOAD10(A, 0)    // steps 0..39
    LOAD10(B, 40)   // steps 40..79

    // 12 iterations x 80 steps = 960, then a 40-step tail from A.
    for (int it = 0; it < 12; ++it) {
        const int base = it * 80;
        const int nb = (it < 11) ? base + 120 : 960;  // clamped; stale unused

        RUN40(A)                    // steps base .. base+39
        LOAD10(A, base + 80)        // it=11 loads steps 960..999 (the tail)
        RUN40(B)                    // steps base+40 .. base+79
        LOAD10(B, nb)
    }
    RUN40(A)                        // steps 960..999

#undef RUN40
#undef RUN4
#undef STEP_E
#undef STEP_O
#undef LOAD10

    keep5(we0); keep5(we1); keep5(we2); keep5(we3); keep5(we4);
    keep5(wo0); keep5(wo1); keep5(wo2); keep5(wo3); keep5(wo4);
    keep5(wie); keep5(bie); keep5(wio); keep5(bio);

    // After step 999 (odd role), lane (a,bq) holds h[bq-slice] replicated
    // over a. Mask fc weights to a==0 lanes, dot, reduce across the group.
    float dot;
    {
        const float* pf = fc_w + bq * 5;
        float f0 = oact ? pf[0] : 0.f, f1 = oact ? pf[1] : 0.f;
        float f2 = oact ? pf[2] : 0.f, f3 = oact ? pf[3] : 0.f;
        float f4 = oact ? pf[4] : 0.f;
        dot = h.v0 * f0;
        dot = __builtin_fmaf(h.v1, f1, dot);
        dot = __builtin_fmaf(h.v2, f2, dot);
        dot = __builtin_fmaf(h.v3, f3, dot);
        dot = __builtin_fmaf(h.v4, f4, dot);
    }
    dot += __shfl_xor(dot, 1, 16);
    dot += __shfl_xor(dot, 2, 16);
    dot += __shfl_xor(dot, 4, 16);
    dot += __shfl_xor(dot, 8, 16);

    if (gl == 0)
        out[b] = dot + fc_b[0];
}

extern "C" void kernel_launch(void* const* d_in, const int* in_sizes, int n_in,
                              void* d_out, int out_size, void* d_ws, size_t ws_size,
                              hipStream_t stream) {
    const float* x    = (const float*)d_in[0];
    const float* W_ih = (const float*)d_in[1];
    const float* W_hh = (const float*)d_in[2];
    const float* b_ih = (const float*)d_in[3];
    const float* b_hh = (const float*)d_in[4];
    const float* fc_w = (const float*)d_in[5];
    const float* fc_b = (const float*)d_in[6];
    float* out = (float*)d_out;

    // 4096 batches * 16 lanes = 65536 threads; 64-thread blocks -> 1024
    // single-wave blocks, one per SIMD.
    const int block = 64;
    const int grid  = (4096 * 16) / block;  // 1024 blocks
    rnn_d40_kernel<<<grid, block, 0, stream>>>(x, W_ih, W_hh, b_ih, b_hh,
                                               fc_w, fc_b, out);
}

// Round 14
// 147.082 us; speedup vs baseline: 1.1511x; 1.0802x over previous
//
#include <hip/hip_runtime.h>

// RNN: h_{t+1} = relu(x_t*W_ih^T + b_ih + b_hh + W_hh·h_t), out = fc(h_T).
// B=4096, T=1000, H=20.  16 lanes per batch, 1024 waves = 1 per SIMD.
//
// Alternating-role scheme: lane (a,bq) of each 16-lane group:
//   EVEN step: rows a-group x k-slice bq; reduce over bq = quad_perm butterfly.
//   ODD  step: rows bq-group x k-slice a; reduce over a = row_ror:4/8 folds.
//
// R13 best = 100 us (intrinsic folds + 40-step prefetch blocks).
// R14: PACKED FP32. CDNA v_pk_fma_f32 / v_pk_max_f32 do 2 fp32 ops per
// instruction; LLVM selects them from <2 x float> fma/max. Accumulators
// paired as (a0,a1),(a2,a3),a4: step drops from 45 to ~31 VALU insts.
// Folds remain scalar DPP (32-bit); half-extraction of a pair is free.
// Intrinsics only -- R10-R12 showed inline asm costs ~10% in lost scheduling.

#define TT 1000

typedef float v2f __attribute__((ext_vector_type(2)));

// one column k of a 5x5 tile: rows 0..4 packed as (r0,r1),(r2,r3),r4
struct Col { v2f p01, p23; float v4; };

#define PIN(v)  asm volatile("" : "+v"(v))
__device__ __forceinline__ void pinc(Col& c) {
    PIN(c.p01); PIN(c.p23); PIN(c.v4);
}
__device__ __forceinline__ void keepc(const Col& c) {
    asm volatile("" :: "v"(c.p01), "v"(c.p23), "v"(c.v4));
}

template <int CTRL>
__device__ __forceinline__ float dpp_f(float v) {
    // old=0 + bound_ctrl + full masks -> GCNDPPCombine fuses into v_add_f32_dpp
    return __int_as_float(__builtin_amdgcn_update_dpp(
        0, __float_as_int(v), CTRL, 0xF, 0xF, true));
}

#define QP_XOR1 0xB1   // quad_perm [1,0,3,2]
#define QP_XOR2 0x4E   // quad_perm [2,3,0,1]
#define ROR4   0x124   // row_ror:4  (within 16-lane row)
#define ROR8   0x128   // row_ror:8

// One timestep. h = (h01,h23,h4). Columns wc0..wc4, packed.
template <int C1, int C2>
__device__ __forceinline__ void step(float xt, v2f& h01, v2f& h23, float& h4,
                                     const Col& wc0, const Col& wc1,
                                     const Col& wc2, const Col& wc3,
                                     const Col& wc4,
                                     const Col& wih, const Col& bias) {
    const v2f xs = {xt, xt};
    v2f  A01 = __builtin_elementwise_fma(xs, wih.p01, bias.p01);
    v2f  A23 = __builtin_elementwise_fma(xs, wih.p23, bias.p23);
    float a4 = __builtin_fmaf(xt, wih.v4, bias.v4);

#define KCOL(hk, wc) {                                             \
        const v2f hs = {hk, hk};                                   \
        A01 = __builtin_elementwise_fma(hs, (wc).p01, A01);        \
        A23 = __builtin_elementwise_fma(hs, (wc).p23, A23);        \
        a4  = __builtin_fmaf(hk, (wc).v4, a4); }
    KCOL(h01.x, wc0) KCOL(h01.y, wc1) KCOL(h23.x, wc2) KCOL(h23.y, wc3) KCOL(h4, wc4)
#undef KCOL

    // folds on the five 32-bit halves (breadth-first: movs then adds)
    float b0 = A01.x, b1 = A01.y, b2 = A23.x, b3 = A23.y, b4 = a4;
    {
        float t0 = dpp_f<C1>(b0), t1 = dpp_f<C1>(b1), t2 = dpp_f<C1>(b2),
              t3 = dpp_f<C1>(b3), t4 = dpp_f<C1>(b4);
        b0 += t0; b1 += t1; b2 += t2; b3 += t3; b4 += t4;
    }
    {
        float t0 = dpp_f<C2>(b0), t1 = dpp_f<C2>(b1), t2 = dpp_f<C2>(b2),
              t3 = dpp_f<C2>(b3), t4 = dpp_f<C2>(b4);
        b0 += t0; b1 += t1; b2 += t2; b3 += t3; b4 += t4;
    }

    const v2f z = {0.f, 0.f};
    v2f r01 = {b0, b1};
    v2f r23 = {b2, b3};
    h01 = __builtin_elementwise_max(r01, z);   // v_pk_max_f32
    h23 = __builtin_elementwise_max(r23, z);
    h4  = fmaxf(b4, 0.f);
}

__global__ void
__attribute__((amdgpu_flat_work_group_size(64, 64), amdgpu_waves_per_eu(1, 1)))
rnn_pk_kernel(const float* __restrict__ x,
              const float* __restrict__ W_ih,
              const float* __restrict__ W_hh,
              const float* __restrict__ b_ih,
              const float* __restrict__ b_hh,
              const float* __restrict__ fc_w,
              const float* __restrict__ fc_b,
              float* __restrict__ out) {
    const int tid = blockIdx.x * 64 + threadIdx.x;
    const int b   = tid >> 4;     // batch element
    const int gl  = tid & 15;     // lane in 16-lane group
    const int a   = gl >> 2;      // quad index
    const int bq  = gl & 3;       // position in quad

    // --- weight tiles, column-major, packed rows
    Col we0, we1, we2, we3, we4;  // even: rows a-group, cols bq-group
    Col wo0, wo1, wo2, wo3, wo4;  // odd:  rows bq-group, cols a-group
#define LOADC(wk, k, rbase, cbase)                                            \
    { (wk).p01 = (v2f){ W_hh[((rbase) + 0) * 20 + (cbase) + (k)],             \
                        W_hh[((rbase) + 1) * 20 + (cbase) + (k)] };           \
      (wk).p23 = (v2f){ W_hh[((rbase) + 2) * 20 + (cbase) + (k)],             \
                        W_hh[((rbase) + 3) * 20 + (cbase) + (k)] };           \
      (wk).v4  =        W_hh[((rbase) + 4) * 20 + (cbase) + (k)]; }
    LOADC(we0, 0, a * 5, bq * 5) LOADC(we1, 1, a * 5, bq * 5)
    LOADC(we2, 2, a * 5, bq * 5) LOADC(we3, 3, a * 5, bq * 5)
    LOADC(we4, 4, a * 5, bq * 5)
    LOADC(wo0, 0, bq * 5, a * 5) LOADC(wo1, 1, bq * 5, a * 5)
    LOADC(wo2, 2, bq * 5, a * 5) LOADC(wo3, 3, bq * 5, a * 5)
    LOADC(wo4, 4, bq * 5, a * 5)
#undef LOADC

    const bool eact = (bq == 0);  // even steps: reduction over bq
    const bool oact = (a == 0);   // odd steps:  reduction over a
    Col wie, bie, wio, bio;
#define LOADIB(wv, bv, base, act)                                             \
    { const float* pw = W_ih + (base);                                        \
      const float* p1 = b_ih + (base);                                        \
      const float* p2 = b_hh + (base);                                        \
      (wv).p01 = (v2f){ (act) ? pw[0] : 0.f, (act) ? pw[1] : 0.f };           \
      (wv).p23 = (v2f){ (act) ? pw[2] : 0.f, (act) ? pw[3] : 0.f };           \
      (wv).v4  =        (act) ? pw[4] : 0.f;                                  \
      (bv).p01 = (v2f){ (act) ? (p1[0] + p2[0]) : 0.f,                        \
                        (act) ? (p1[1] + p2[1]) : 0.f };                      \
      (bv).p23 = (v2f){ (act) ? (p1[2] + p2[2]) : 0.f,                        \
                        (act) ? (p1[3] + p2[3]) : 0.f };                      \
      (bv).v4  =        (act) ? (p1[4] + p2[4]) : 0.f; }
    LOADIB(wie, bie, a * 5,  eact)
    LOADIB(wio, bio, bq * 5, oact)
#undef LOADIB

    pinc(we0); pinc(we1); pinc(we2); pinc(we3); pinc(we4);
    pinc(wo0); pinc(wo1); pinc(wo2); pinc(wo3); pinc(wo4);
    pinc(wie); pinc(bie); pinc(wio); pinc(bio);

    v2f h01 = {0.f, 0.f}, h23 = {0.f, 0.f};
    float h4 = 0.f;

    const float* __restrict__ xb = x + (size_t)b * TT;

    // --- 40-step register blocks (10 float4 each), double-buffered (R13)
#define LOAD10(P, off)                                  \
    P##0 = *(const float4*)(xb + (off));                \
    P##1 = *(const float4*)(xb + (off) + 4);            \
    P##2 = *(const float4*)(xb + (off) + 8);            \
    P##3 = *(const float4*)(xb + (off) + 12);           \
    P##4 = *(const float4*)(xb + (off) + 16);           \
    P##5 = *(const float4*)(xb + (off) + 20);           \
    P##6 = *(const float4*)(xb + (off) + 24);           \
    P##7 = *(const float4*)(xb + (off) + 28);           \
    P##8 = *(const float4*)(xb + (off) + 32);           \
    P##9 = *(const float4*)(xb + (off) + 36);

#define STEP_E(xv) step<QP_XOR1, QP_XOR2>(xv, h01, h23, h4, we0, we1, we2, we3, we4, wie, bie);
#define STEP_O(xv) step<ROR4,    ROR8   >(xv, h01, h23, h4, wo0, wo1, wo2, wo3, wo4, wio, bio);
#define RUN4(Q)  STEP_E(Q.x) STEP_O(Q.y) STEP_E(Q.z) STEP_O(Q.w)
#define RUN40(P) RUN4(P##0) RUN4(P##1) RUN4(P##2) RUN4(P##3) RUN4(P##4) \
                 RUN4(P##5) RUN4(P##6) RUN4(P##7) RUN4(P##8) RUN4(P##9)

    float4 A0, A1, A2, A3, A4, A5, A6, A7, A8, A9;
    float4 B0, B1, B2, B3, B4, B5, B6, B7, B8, B9;
    LOAD10(A, 0)    // steps 0..39
    LOAD10(B, 40)   // steps 40..79

    // 12 iterations x 80 steps = 960, then a 40-step tail from A.
    for (int it = 0; it < 12; ++it) {
        const int base = it * 80;
        const int nb = (it < 11) ? base + 120 : 960;  // clamped; stale unused

        RUN40(A)                    // steps base .. base+39
        LOAD10(A, base + 80)        // it=11 loads steps 960..999 (the tail)
        RUN40(B)                    // steps base+40 .. base+79
        LOAD10(B, nb)
    }
    RUN40(A)                        // steps 960..999

#undef RUN40
#undef RUN4
#undef STEP_E
#undef STEP_O
#undef LOAD10

    keepc(we0); keepc(we1); keepc(we2); keepc(we3); keepc(we4);
    keepc(wo0); keepc(wo1); keepc(wo2); keepc(wo3); keepc(wo4);
    keepc(wie); keepc(bie); keepc(wio); keepc(bio);

    // After step 999 (odd role), lane (a,bq) holds h[bq-slice] replicated
    // over a. Mask fc weights to a==0 lanes, dot, reduce across the group.
    float dot;
    {
        const float* pf = fc_w + bq * 5;
        float f0 = oact ? pf[0] : 0.f, f1 = oact ? pf[1] : 0.f;
        float f2 = oact ? pf[2] : 0.f, f3 = oact ? pf[3] : 0.f;
        float f4 = oact ? pf[4] : 0.f;
        dot = h01.x * f0;
        dot = __builtin_fmaf(h01.y, f1, dot);
        dot = __builtin_fmaf(h23.x, f2, dot);
        dot = __builtin_fmaf(h23.y, f3, dot);
        dot = __builtin_fmaf(h4,    f4, dot);
    }
    dot += __shfl_xor(dot, 1, 16);
    dot += __shfl_xor(dot, 2, 16);
    dot += __shfl_xor(dot, 4, 16);
    dot += __shfl_xor(dot, 8, 16);

    if (gl == 0)
        out[b] = dot + fc_b[0];
}

extern "C" void kernel_launch(void* const* d_in, const int* in_sizes, int n_in,
                              void* d_out, int out_size, void* d_ws, size_t ws_size,
                              hipStream_t stream) {
    const float* x    = (const float*)d_in[0];
    const float* W_ih = (const float*)d_in[1];
    const float* W_hh = (const float*)d_in[2];
    const float* b_ih = (const float*)d_in[3];
    const float* b_hh = (const float*)d_in[4];
    const float* fc_w = (const float*)d_in[5];
    const float* fc_b = (const float*)d_in[6];
    float* out = (float*)d_out;

    // 4096 batches * 16 lanes = 65536 threads; 64-thread blocks -> 1024
    // single-wave blocks, one per SIMD.
    const int block = 64;
    const int grid  = (4096 * 16) / block;  // 1024 blocks
    rnn_pk_kernel<<<grid, block, 0, stream>>>(x, W_ih, W_hh, b_ih, b_hh,
                                              fc_w, fc_b, out);
}